// Round 7
// baseline (724.696 us; speedup 1.0000x reference)
//
#include <hip/hip_runtime.h>

// DCNv2 forward, MI355X (gfx950).
//  k_pre:        x NCHW f32 -> xbf NHWC bf16 (transpose role) + coalesced weight
//                repack via LDS (one block per oc; c=t, kk=j from idx=9t+j).
//  k_offconv:    implicit-im2col MFMA GEMM -> om[r][32] f32 (bias+sigmoid).
//                1024 thr, K-split-4 (4 wave-groups x 9 ksteps), depth-2 reg
//                prefetch, RAW barriers, 3-partial LDS reduction.
//  k_gemm_fused: deformable-im2col fused GEMM. 1024 thr = 16 waves, K-split-2,
//                XOR-swizzled LDS, RAW barriers (lgkmcnt-only), DEPTH-2 A-gather
//                prefetch (blend k uses gathers issued at k-2 -> no vmcnt stall),
//                om params prefetched one kk ahead, perm-packed bf16 blend.

typedef __bf16 bf16x8 __attribute__((ext_vector_type(8)));
typedef float  f32x4  __attribute__((ext_vector_type(4)));
typedef unsigned short ushort8 __attribute__((ext_vector_type(8)));
typedef unsigned int   uint4v  __attribute__((ext_vector_type(4)));

#define XBF_OFF   0u            // 4*4096*256*2  = 8,388,608
#define WREP_OFF  8388608u      // 32*2304*2     =   147,456
#define WMAIN_OFF 8536064u      // 256*2304*2    = 1,179,648
#define OM_OFF    9715712u      // 16384*32*4    = 2,097,152

// wait lgkmcnt(0) only (vmcnt=no wait), then barrier: LDS visibility without
// draining in-flight global gathers.
#define LGKM0_BAR() do { __builtin_amdgcn_s_waitcnt(0xC07F); __builtin_amdgcn_s_barrier(); } while (0)

__device__ __forceinline__ unsigned short f2bf(float f) {
  unsigned int u = __float_as_uint(f);
  u += 0x7fffu + ((u >> 16) & 1u);
  return (unsigned short)(u >> 16);
}
__device__ __forceinline__ float bf2f(unsigned short h) {
  return __uint_as_float(((unsigned int)h) << 16);
}

// ---------------- merged transpose + coalesced repack ----------------
__global__ __launch_bounds__(256) void k_pre(const float* __restrict__ x,
                                             const float* __restrict__ w_off,
                                             const float* __restrict__ dcn_w,
                                             unsigned short* __restrict__ xbf,
                                             unsigned short* __restrict__ wrep,
                                             unsigned short* __restrict__ wmain) {
  __shared__ float tile[32][65];
  __shared__ unsigned short lsh[2304];
  int b = blockIdx.x;
  int t = threadIdx.x;
  if (b < 2048) {               // transpose role
    int n  = b >> 9;
    int cb = (b >> 6) & 7;
    int xb = b & 63;
    int xx  = t & 63;
    int cc0 = t >> 6;
#pragma unroll
    for (int j = 0; j < 8; ++j) {
      int cc = cc0 + j * 4;
      tile[cc][xx] = x[((size_t)(n * 256 + cb * 32 + cc) << 12) + xb * 64 + xx];
    }
    __syncthreads();
    int ccw = t & 31;
    int xw0 = t >> 5;
#pragma unroll
    for (int j = 0; j < 8; ++j) {
      int xw = xw0 + j * 8;
      xbf[((size_t)((n << 12) + xb * 64 + xw)) * 256 + cb * 32 + ccw] = f2bf(tile[ccw][xw]);
    }
  } else {                      // repack role: one block per output channel
    int ocb = b - 2048;
    const float* src;
    unsigned short* dst;
    int oc;
    if (ocb < 32) { oc = ocb; src = w_off; dst = wrep; }
    else          { oc = ocb - 32; src = dcn_w; dst = wmain; }
    if (ocb < 32 && oc >= 27) {           // zero-pad rows of wrep
#pragma unroll
      for (int j = 0; j < 9; ++j) dst[oc * 2304 + j * 256 + t] = 0;
      return;
    }
    const float* base = src + (size_t)oc * 2304;
    // idx = 9t+j = c*9+kk  ->  c = t, kk = j : contiguous reads per wave
#pragma unroll
    for (int j = 0; j < 9; ++j) lsh[j * 256 + t] = f2bf(base[t * 9 + j]);
    __syncthreads();
#pragma unroll
    for (int j = 0; j < 9; ++j) dst[oc * 2304 + j * 256 + t] = lsh[j * 256 + t];
  }
}

// ---------------- offset-field conv: K-split-4, BK=64, depth-2 prefetch ------
__global__ __launch_bounds__(1024) void k_offconv(const unsigned short* __restrict__ xbf,
                                                  const unsigned short* __restrict__ wrep,
                                                  const float* __restrict__ bias,
                                                  float* __restrict__ om) {
  __shared__ __align__(16) unsigned short SHa[4][64 * 64];   // 32 KB
  __shared__ __align__(16) unsigned short SHb[4][32 * 64];   // 16 KB
  int t = threadIdx.x;
  int wave = t >> 6, lane = t & 63;
  int grp = wave >> 2, wv = wave & 3;
  int tg = t & 255;
  int bm = ((blockIdx.x & 7) << 5) + (blockIdx.x >> 3);   // XCD swizzle
  int n = bm >> 6, oy = bm & 63;

  unsigned short* As = SHa[grp];
  unsigned short* Bs = SHb[grp];

  int arow = tg >> 2, acc4 = tg & 3;
  int brow = tg >> 3, bch = tg & 7;

  f32x4 acc0 = {0.f, 0.f, 0.f, 0.f};
  f32x4 acc1 = {0.f, 0.f, 0.f, 0.f};

  ushort8 av[2][2]; ushort8 bv[2];
  auto prefetch = [&](int ktg, int slot) {
    int kk = ktg >> 2;
    int c0 = (ktg & 3) * 64;
    int dy = kk / 3 - 1, dx = kk % 3 - 1;
    int yy = oy + dy, xxg = arow + dx;
    bool ok = ((unsigned)yy < 64u) && ((unsigned)xxg < 64u);
    const unsigned short* p = xbf + (size_t)(((n * 64 + yy) * 64 + xxg) * 256 + c0 + acc4 * 16);
#pragma unroll
    for (int g = 0; g < 2; ++g)
      av[slot][g] = ok ? *(const ushort8*)(p + g * 8) : (ushort8){0,0,0,0,0,0,0,0};
    bv[slot] = *(const ushort8*)(wrep + (size_t)brow * 2304 + ktg * 64 + bch * 8);
  };

  int k0 = grp * 9;
  prefetch(k0, 0);
  prefetch(k0 + 1, 1);
  int mr = lane & 15, q = lane >> 4;
  for (int kt = 0; kt < 9; ++kt) {
    int slot = kt & 1;
    LGKM0_BAR();
#pragma unroll
    for (int g = 0; g < 2; ++g) {
      int ch = (acc4 * 2 + g) ^ (arow & 7);
      *(ushort8*)&As[arow * 64 + ch * 8] = av[slot][g];
    }
    { int ch = bch ^ (brow & 7);
      *(ushort8*)&Bs[brow * 64 + ch * 8] = bv[slot]; }
    if (kt + 2 < 9) prefetch(k0 + kt + 2, slot);
    LGKM0_BAR();
#pragma unroll
    for (int kh = 0; kh < 2; ++kh) {
      int coff = ((q + kh * 4) ^ (mr & 7)) * 8;
      bf16x8 a  = *(const bf16x8*)&As[(wv * 16 + mr) * 64 + coff];
      bf16x8 b0 = *(const bf16x8*)&Bs[mr * 64 + coff];
      bf16x8 b1 = *(const bf16x8*)&Bs[(16 + mr) * 64 + coff];
      acc0 = __builtin_amdgcn_mfma_f32_16x16x32_bf16(a, b0, acc0, 0, 0, 0);
      acc1 = __builtin_amdgcn_mfma_f32_16x16x32_bf16(a, b1, acc1, 0, 0, 0);
    }
  }
  // 3 partials -> scratch (24 KB <= SHa's 32 KB), group 0 reduces + epilogue
  float* scratch = (float*)&SHa[0][0];
  __syncthreads();
  if (grp > 0) {
#pragma unroll
    for (int nt = 0; nt < 2; ++nt) {
      f32x4 a = nt ? acc1 : acc0;
#pragma unroll
      for (int rg = 0; rg < 4; ++rg)
        scratch[(grp - 1) * 2048 + (wv * 16 + q * 4 + rg) * 32 + nt * 16 + mr] = a[rg];
    }
  }
  __syncthreads();
  if (grp == 0) {
    int r0 = bm * 64;
#pragma unroll
    for (int nt = 0; nt < 2; ++nt) {
      f32x4 a = nt ? acc1 : acc0;
      int oc = nt * 16 + mr;
      float bvl = (oc < 27) ? bias[oc] : 0.f;
#pragma unroll
      for (int rg = 0; rg < 4; ++rg) {
        int pl = wv * 16 + q * 4 + rg;
        float v = a[rg] + bvl + scratch[pl * 32 + oc] +
                  scratch[2048 + pl * 32 + oc] + scratch[4096 + pl * 32 + oc];
        if (oc >= 18 && oc < 27) v = 1.f / (1.f + __expf(-v));
        om[(r0 + pl) * 32 + oc] = v;
      }
    }
  }
}

// ---------------- fused deformable-im2col GEMM, depth-2 pipeline -------------
__global__ __launch_bounds__(1024) void k_gemm_fused(const unsigned short* __restrict__ xbf,
                                                     const float* __restrict__ om,
                                                     const unsigned short* __restrict__ wB,
                                                     float* __restrict__ out) {
  __shared__ __align__(16) unsigned short SH[4][128 * 64];  // [A g0][A g1][B g0][B g1]
  int t = threadIdx.x;
  int wave = t >> 6, lane = t & 63;
  int grp = wave >> 3, wv = wave & 7;
  int wm = wv & 1, wn = wv >> 1;
  int tg = t & 511;
  int bmx = ((blockIdx.x & 7) << 4) + (blockIdx.x >> 3);    // XCD swizzle
  int r0 = bmx * 128, o0 = blockIdx.y * 128;

  unsigned short* As = SH[grp];
  unsigned short* Bs = SH[2 + grp];

  int srow = tg >> 2, sc4 = tg & 3;
  int r = r0 + srow;
  int n = r >> 12, yx = r & 4095, oy = yx >> 6, ox = yx & 63;
  const unsigned short* xb = xbf + (size_t)n * (4096 * 256);
  const float* omr = om + (size_t)r * 32;
  const unsigned short* Bg = wB + (size_t)(o0 + srow) * 2304 + sc4 * 16;

  f32x4 acc[4][2];
#pragma unroll
  for (int mt = 0; mt < 4; ++mt)
#pragma unroll
    for (int nt = 0; nt < 2; ++nt) acc[mt][nt] = (f32x4){0.f, 0.f, 0.f, 0.f};

  // om params: pv_* prefetched one kk ahead; cw/a = current kk's weights+addrs
  float pv_y, pv_x, pv_m;
  float cw1, cw2, cw3, cw4;
  int a1, a2, a3, a4;
  float wbuf[2][4];

  auto loadom = [&](int kk) {
    pv_y = omr[2 * kk]; pv_x = omr[2 * kk + 1]; pv_m = omr[18 + kk];
  };
  auto params = [&](int kk) {        // consumes pv_* (already resident)
    float py = (float)(oy + kk / 3) + pv_y;
    float px = (float)(ox + kk % 3) + pv_x;
    float m = pv_m;
    py = fminf(fmaxf(py, 0.f), 65.f);
    px = fminf(fmaxf(px, 0.f), 65.f);
    float fy = floorf(py), fx = floorf(px);
    float ly = py - fy, lx = px - fx;
    float hy = 1.f - ly, hx = 1.f - lx;
    int iy = (int)fy, ix = (int)fx;
    bool yv0 = (iy >= 1) && (iy <= 64);
    bool yv1 = (iy <= 63);
    bool xv0 = (ix >= 1) && (ix <= 64);
    bool xv1 = (ix <= 63);
    int y0 = min(max(iy - 1, 0), 63);
    int y1 = min(iy, 63);
    int x0 = min(max(ix - 1, 0), 63);
    int x1 = min(ix, 63);
    cw1 = (yv0 && xv0) ? hy * hx * m : 0.f;
    cw2 = (yv0 && xv1) ? hy * lx * m : 0.f;
    cw3 = (yv1 && xv0) ? ly * hx * m : 0.f;
    cw4 = (yv1 && xv1) ? ly * lx * m : 0.f;
    a1 = ((y0 << 6) + x0) * 256;
    a2 = ((y0 << 6) + x1) * 256;
    a3 = ((y1 << 6) + x0) * 256;
    a4 = ((y1 << 6) + x1) * 256;
  };

  ushort8 g1[2][2], g2[2][2], g3[2][2], g4[2][2];  // [slot][chunk]
  ushort8 bv[2];                                   // [chunk], depth-1
  auto issueA = [&](int ktg2, int slot, bool doParams) {
    if (doParams) {
      int kk = ktg2 >> 2;
      params(kk);
      loadom(kk < 8 ? kk + 1 : 8);
    }
    wbuf[slot][0] = cw1; wbuf[slot][1] = cw2; wbuf[slot][2] = cw3; wbuf[slot][3] = cw4;
    int c0 = (ktg2 & 3) * 64 + sc4 * 16;
#pragma unroll
    for (int g = 0; g < 2; ++g) {
      int c = c0 + g * 8;
      g1[slot][g] = *(const ushort8*)(xb + a1 + c);
      g2[slot][g] = *(const ushort8*)(xb + a2 + c);
      g3[slot][g] = *(const ushort8*)(xb + a3 + c);
      g4[slot][g] = *(const ushort8*)(xb + a4 + c);
    }
  };
  auto prefB = [&](int ktg2) {
#pragma unroll
    for (int g = 0; g < 2; ++g)
      bv[g] = *(const ushort8*)(Bg + ktg2 * 64 + g * 8);
  };

  int ktg0 = grp * 18;
  int kk0 = ktg0 >> 2;
  loadom(kk0);
  params(kk0);
  loadom(kk0 < 8 ? kk0 + 1 : 8);
  issueA(ktg0, 0, false);
  issueA(ktg0 + 1, 1, false);
  prefB(ktg0);

  int mr = lane & 15, q = lane >> 4;
  for (int kt = 0; kt < 18; ++kt) {
    int ktg = ktg0 + kt;
    int slot = kt & 1;
    // blend + perm-pack: gathers were issued at kt-2 -> vmcnt wait ~0
    uint4v rs[2];
#pragma unroll
    for (int g = 0; g < 2; ++g) {
#pragma unroll
      for (int p = 0; p < 4; ++p) {
        float va = wbuf[slot][0] * bf2f(g1[slot][g][2 * p])     + wbuf[slot][1] * bf2f(g2[slot][g][2 * p]) +
                   wbuf[slot][2] * bf2f(g3[slot][g][2 * p])     + wbuf[slot][3] * bf2f(g4[slot][g][2 * p]);
        float vb = wbuf[slot][0] * bf2f(g1[slot][g][2 * p + 1]) + wbuf[slot][1] * bf2f(g2[slot][g][2 * p + 1]) +
                   wbuf[slot][2] * bf2f(g3[slot][g][2 * p + 1]) + wbuf[slot][3] * bf2f(g4[slot][g][2 * p + 1]);
        unsigned ua = __float_as_uint(va) + 0x8000u;
        unsigned ub = __float_as_uint(vb) + 0x8000u;
        rs[g][p] = __builtin_amdgcn_perm(ub, ua, 0x07060302u);
      }
    }
    // issue A gathers for kt+2 (2 ksteps of cover)
    if (kt + 2 < 18) issueA(ktg + 2, slot, ((ktg + 2) & 3) == 0);
    LGKM0_BAR();                 // all waves done reading LDS tile kt-1
#pragma unroll
    for (int g = 0; g < 2; ++g) {
      int ch = (sc4 * 2 + g) ^ (srow & 7);
      *(uint4v*)&As[srow * 64 + ch * 8] = rs[g];
      *(ushort8*)&Bs[srow * 64 + ch * 8] = bv[g];
    }
    if (kt + 1 < 18) prefB(ktg + 1);
    LGKM0_BAR();                 // writes visible
#pragma unroll
    for (int kh = 0; kh < 2; ++kh) {
      int coff = ((q + kh * 4) ^ (mr & 7)) * 8;
      bf16x8 af[4], bfv[2];
#pragma unroll
      for (int mt = 0; mt < 4; ++mt)
        af[mt] = *(const bf16x8*)&As[(wm * 64 + mt * 16 + mr) * 64 + coff];
#pragma unroll
      for (int nt = 0; nt < 2; ++nt)
        bfv[nt] = *(const bf16x8*)&Bs[(wn * 32 + nt * 16 + mr) * 64 + coff];
#pragma unroll
      for (int mt = 0; mt < 4; ++mt)
#pragma unroll
        for (int nt = 0; nt < 2; ++nt)
          acc[mt][nt] = __builtin_amdgcn_mfma_f32_16x16x32_bf16(af[mt], bfv[nt], acc[mt][nt], 0, 0, 0);
    }
  }

  // reduce K-partials through LDS
  float* scratch = (float*)&SH[0][0];
  __syncthreads();
  if (grp == 1) {
#pragma unroll
    for (int mt = 0; mt < 4; ++mt)
#pragma unroll
      for (int nt = 0; nt < 2; ++nt) {
        int pl = wm * 64 + mt * 16 + q * 4;
        int ol = wn * 32 + nt * 16 + mr;
#pragma unroll
        for (int rg = 0; rg < 4; ++rg)
          scratch[(pl + rg) * 128 + ol] = acc[mt][nt][rg];
      }
  }
  __syncthreads();
  if (grp == 0) {
#pragma unroll
    for (int mt = 0; mt < 4; ++mt)
#pragma unroll
      for (int nt = 0; nt < 2; ++nt) {
        int pl = wm * 64 + mt * 16 + q * 4;
        int ol = wn * 32 + nt * 16 + mr;
        f32x4 v = acc[mt][nt];
#pragma unroll
        for (int rg = 0; rg < 4; ++rg) v[rg] += scratch[(pl + rg) * 128 + ol];
        int p = r0 + pl;
        int o = o0 + ol;
        int nn = p >> 12, pyx = p & 4095;
        *(f32x4*)(out + ((size_t)(nn * 256 + o) << 12) + pyx) = v;
      }
  }
}

extern "C" void kernel_launch(void* const* d_in, const int* in_sizes, int n_in,
                              void* d_out, int out_size, void* d_ws, size_t ws_size,
                              hipStream_t stream) {
  const float* x     = (const float*)d_in[0];
  const float* w_off = (const float*)d_in[1];
  const float* b_off = (const float*)d_in[2];
  const float* dcn_w = (const float*)d_in[3];
  float* out = (float*)d_out;
  char* ws = (char*)d_ws;
  unsigned short* xbf   = (unsigned short*)(ws + XBF_OFF);
  unsigned short* wrep  = (unsigned short*)(ws + WREP_OFF);
  unsigned short* wmain = (unsigned short*)(ws + WMAIN_OFF);
  float*          om    = (float*)(ws + OM_OFF);

  k_pre<<<2048 + 288, 256, 0, stream>>>(x, w_off, dcn_w, xbf, wrep, wmain);
  k_offconv<<<256, 1024, 0, stream>>>(xbf, wrep, b_off, om);
  k_gemm_fused<<<dim3(128, 2), 1024, 0, stream>>>(xbf, om, wmain, out);
}

// Round 8
// 342.339 us; speedup vs baseline: 2.1169x; 2.1169x over previous
//
#include <hip/hip_runtime.h>
#include <type_traits>

// DCNv2 forward, MI355X (gfx950).
//  k_pre:        x NCHW f32 -> xbf NHWC bf16 (transpose role) + coalesced weight
//                repack via LDS (one block per oc).
//  k_offconv:    implicit-im2col MFMA GEMM -> om[r][32] f32 (bias+sigmoid).
//                1024 thr, K-split-4, depth-2 reg prefetch (loop fully unrolled
//                so prefetch slots are compile-time -> stay in VGPRs).
//  k_gemm_fused: deformable-im2col fused GEMM. 1024 thr = 16 waves, K-split-2,
//                XOR-swizzled LDS, RAW barriers (lgkmcnt-only), depth-2 A-gather
//                prefetch. CRITICAL: K-loop runs as 9 explicit (slot0, slot1)
//                pairs with slot as integral_constant — runtime slot indexing
//                previously demoted all prefetch state to scratch (R7: 2 GB of
//                spill traffic, 727 us).

typedef __bf16 bf16x8 __attribute__((ext_vector_type(8)));
typedef float  f32x4  __attribute__((ext_vector_type(4)));
typedef unsigned short ushort8 __attribute__((ext_vector_type(8)));
typedef unsigned int   uint4v  __attribute__((ext_vector_type(4)));

#define XBF_OFF   0u            // 4*4096*256*2  = 8,388,608
#define WREP_OFF  8388608u      // 32*2304*2     =   147,456
#define WMAIN_OFF 8536064u      // 256*2304*2    = 1,179,648
#define OM_OFF    9715712u      // 16384*32*4    = 2,097,152

// wait lgkmcnt(0) only (vmcnt=no wait), then barrier: LDS visibility without
// draining in-flight global gathers.
#define LGKM0_BAR() do { __builtin_amdgcn_s_waitcnt(0xC07F); __builtin_amdgcn_s_barrier(); } while (0)

template <int N> using ic = std::integral_constant<int, N>;

__device__ __forceinline__ unsigned short f2bf(float f) {
  unsigned int u = __float_as_uint(f);
  u += 0x7fffu + ((u >> 16) & 1u);
  return (unsigned short)(u >> 16);
}
__device__ __forceinline__ float bf2f(unsigned short h) {
  return __uint_as_float(((unsigned int)h) << 16);
}

// ---------------- merged transpose + coalesced repack ----------------
__global__ __launch_bounds__(256) void k_pre(const float* __restrict__ x,
                                             const float* __restrict__ w_off,
                                             const float* __restrict__ dcn_w,
                                             unsigned short* __restrict__ xbf,
                                             unsigned short* __restrict__ wrep,
                                             unsigned short* __restrict__ wmain) {
  __shared__ float tile[32][65];
  __shared__ unsigned short lsh[2304];
  int b = blockIdx.x;
  int t = threadIdx.x;
  if (b < 2048) {               // transpose role
    int n  = b >> 9;
    int cb = (b >> 6) & 7;
    int xb = b & 63;
    int xx  = t & 63;
    int cc0 = t >> 6;
#pragma unroll
    for (int j = 0; j < 8; ++j) {
      int cc = cc0 + j * 4;
      tile[cc][xx] = x[((size_t)(n * 256 + cb * 32 + cc) << 12) + xb * 64 + xx];
    }
    __syncthreads();
    int ccw = t & 31;
    int xw0 = t >> 5;
#pragma unroll
    for (int j = 0; j < 8; ++j) {
      int xw = xw0 + j * 8;
      xbf[((size_t)((n << 12) + xb * 64 + xw)) * 256 + cb * 32 + ccw] = f2bf(tile[ccw][xw]);
    }
  } else {                      // repack role: one block per output channel
    int ocb = b - 2048;
    const float* src;
    unsigned short* dst;
    int oc;
    if (ocb < 32) { oc = ocb; src = w_off; dst = wrep; }
    else          { oc = ocb - 32; src = dcn_w; dst = wmain; }
    if (ocb < 32 && oc >= 27) {
#pragma unroll
      for (int j = 0; j < 9; ++j) dst[oc * 2304 + j * 256 + t] = 0;
      return;
    }
    const float* base = src + (size_t)oc * 2304;
#pragma unroll
    for (int j = 0; j < 9; ++j) lsh[j * 256 + t] = f2bf(base[t * 9 + j]);
    __syncthreads();
#pragma unroll
    for (int j = 0; j < 9; ++j) dst[oc * 2304 + j * 256 + t] = lsh[j * 256 + t];
  }
}

// ---------------- offset-field conv: K-split-4, BK=64, depth-2 prefetch ------
__global__ __launch_bounds__(1024) void k_offconv(const unsigned short* __restrict__ xbf,
                                                  const unsigned short* __restrict__ wrep,
                                                  const float* __restrict__ bias,
                                                  float* __restrict__ om) {
  __shared__ __align__(16) unsigned short SHa[4][64 * 64];
  __shared__ __align__(16) unsigned short SHb[4][32 * 64];
  int t = threadIdx.x;
  int wave = t >> 6, lane = t & 63;
  int grp = wave >> 2, wv = wave & 3;
  int tg = t & 255;
  int bm = ((blockIdx.x & 7) << 5) + (blockIdx.x >> 3);   // XCD swizzle
  int n = bm >> 6, oy = bm & 63;

  unsigned short* As = SHa[grp];
  unsigned short* Bs = SHb[grp];

  int arow = tg >> 2, acc4 = tg & 3;
  int brow = tg >> 3, bch = tg & 7;

  f32x4 acc0 = {0.f, 0.f, 0.f, 0.f};
  f32x4 acc1 = {0.f, 0.f, 0.f, 0.f};

  ushort8 av[2][2]; ushort8 bv[2];
  auto prefetch = [&](int ktg, auto slotc) {
    constexpr int slot = decltype(slotc)::value;
    int kk = ktg >> 2;
    int c0 = (ktg & 3) * 64;
    int dy = kk / 3 - 1, dx = kk % 3 - 1;
    int yy = oy + dy, xxg = arow + dx;
    bool ok = ((unsigned)yy < 64u) && ((unsigned)xxg < 64u);
    const unsigned short* p = xbf + (size_t)(((n * 64 + yy) * 64 + xxg) * 256 + c0 + acc4 * 16);
#pragma unroll
    for (int g = 0; g < 2; ++g)
      av[slot][g] = ok ? *(const ushort8*)(p + g * 8) : (ushort8){0,0,0,0,0,0,0,0};
    bv[slot] = *(const ushort8*)(wrep + (size_t)brow * 2304 + ktg * 64 + bch * 8);
  };

  int k0 = grp * 9;
  prefetch(k0, ic<0>{});
  prefetch(k0 + 1, ic<1>{});
  int mr = lane & 15, q = lane >> 4;

  auto step = [&](int kt, auto slotc) {
    constexpr int slot = decltype(slotc)::value;
    LGKM0_BAR();
#pragma unroll
    for (int g = 0; g < 2; ++g) {
      int ch = (acc4 * 2 + g) ^ (arow & 7);
      *(ushort8*)&As[arow * 64 + ch * 8] = av[slot][g];
    }
    { int ch = bch ^ (brow & 7);
      *(ushort8*)&Bs[brow * 64 + ch * 8] = bv[slot]; }
    if (kt + 2 < 9) prefetch(k0 + kt + 2, slotc);
    LGKM0_BAR();
#pragma unroll
    for (int kh = 0; kh < 2; ++kh) {
      int coff = ((q + kh * 4) ^ (mr & 7)) * 8;
      bf16x8 a  = *(const bf16x8*)&As[(wv * 16 + mr) * 64 + coff];
      bf16x8 b0 = *(const bf16x8*)&Bs[mr * 64 + coff];
      bf16x8 b1 = *(const bf16x8*)&Bs[(16 + mr) * 64 + coff];
      acc0 = __builtin_amdgcn_mfma_f32_16x16x32_bf16(a, b0, acc0, 0, 0, 0);
      acc1 = __builtin_amdgcn_mfma_f32_16x16x32_bf16(a, b1, acc1, 0, 0, 0);
    }
  };
  for (int kp = 0; kp < 4; ++kp) {
    step(2 * kp, ic<0>{});
    step(2 * kp + 1, ic<1>{});
  }
  step(8, ic<0>{});

  float* scratch = (float*)&SHa[0][0];
  __syncthreads();
  if (grp > 0) {
#pragma unroll
    for (int nt = 0; nt < 2; ++nt) {
      f32x4 a = nt ? acc1 : acc0;
#pragma unroll
      for (int rg = 0; rg < 4; ++rg)
        scratch[(grp - 1) * 2048 + (wv * 16 + q * 4 + rg) * 32 + nt * 16 + mr] = a[rg];
    }
  }
  __syncthreads();
  if (grp == 0) {
    int r0 = bm * 64;
#pragma unroll
    for (int nt = 0; nt < 2; ++nt) {
      f32x4 a = nt ? acc1 : acc0;
      int oc = nt * 16 + mr;
      float bvl = (oc < 27) ? bias[oc] : 0.f;
#pragma unroll
      for (int rg = 0; rg < 4; ++rg) {
        int pl = wv * 16 + q * 4 + rg;
        float v = a[rg] + bvl + scratch[pl * 32 + oc] +
                  scratch[2048 + pl * 32 + oc] + scratch[4096 + pl * 32 + oc];
        if (oc >= 18 && oc < 27) v = 1.f / (1.f + __expf(-v));
        om[(r0 + pl) * 32 + oc] = v;
      }
    }
  }
}

// ---------------- fused deformable-im2col GEMM, depth-2 pipeline -------------
__global__ __launch_bounds__(1024) void k_gemm_fused(const unsigned short* __restrict__ xbf,
                                                     const float* __restrict__ om,
                                                     const unsigned short* __restrict__ wB,
                                                     float* __restrict__ out) {
  __shared__ __align__(16) unsigned short SH[4][128 * 64];  // [A g0][A g1][B g0][B g1]
  int t = threadIdx.x;
  int wave = t >> 6, lane = t & 63;
  int grp = wave >> 3, wv = wave & 7;
  int wm = wv & 1, wn = wv >> 1;
  int tg = t & 511;
  int bmx = ((blockIdx.x & 7) << 4) + (blockIdx.x >> 3);    // XCD swizzle
  int r0 = bmx * 128, o0 = blockIdx.y * 128;

  unsigned short* As = SH[grp];
  unsigned short* Bs = SH[2 + grp];

  int srow = tg >> 2, sc4 = tg & 3;
  int r = r0 + srow;
  int n = r >> 12, yx = r & 4095, oy = yx >> 6, ox = yx & 63;
  const unsigned short* xb = xbf + (size_t)n * (4096 * 256);
  const float* omr = om + (size_t)r * 32;
  const unsigned short* Bg = wB + (size_t)(o0 + srow) * 2304 + sc4 * 16;

  f32x4 acc[4][2];
#pragma unroll
  for (int mt = 0; mt < 4; ++mt)
#pragma unroll
    for (int nt = 0; nt < 2; ++nt) acc[mt][nt] = (f32x4){0.f, 0.f, 0.f, 0.f};

  float pv_y, pv_x, pv_m;
  float cw1, cw2, cw3, cw4;
  int a1, a2, a3, a4;
  float wbuf[2][4];

  auto loadom = [&](int kk) {
    pv_y = omr[2 * kk]; pv_x = omr[2 * kk + 1]; pv_m = omr[18 + kk];
  };
  auto params = [&](int kk) {        // consumes pv_* (already resident)
    float py = (float)(oy + kk / 3) + pv_y;
    float px = (float)(ox + kk % 3) + pv_x;
    float m = pv_m;
    py = fminf(fmaxf(py, 0.f), 65.f);
    px = fminf(fmaxf(px, 0.f), 65.f);
    float fy = floorf(py), fx = floorf(px);
    float ly = py - fy, lx = px - fx;
    float hy = 1.f - ly, hx = 1.f - lx;
    int iy = (int)fy, ix = (int)fx;
    bool yv0 = (iy >= 1) && (iy <= 64);
    bool yv1 = (iy <= 63);
    bool xv0 = (ix >= 1) && (ix <= 64);
    bool xv1 = (ix <= 63);
    int y0 = min(max(iy - 1, 0), 63);
    int y1 = min(iy, 63);
    int x0 = min(max(ix - 1, 0), 63);
    int x1 = min(ix, 63);
    cw1 = (yv0 && xv0) ? hy * hx * m : 0.f;
    cw2 = (yv0 && xv1) ? hy * lx * m : 0.f;
    cw3 = (yv1 && xv0) ? ly * hx * m : 0.f;
    cw4 = (yv1 && xv1) ? ly * lx * m : 0.f;
    a1 = ((y0 << 6) + x0) * 256;
    a2 = ((y0 << 6) + x1) * 256;
    a3 = ((y1 << 6) + x0) * 256;
    a4 = ((y1 << 6) + x1) * 256;
  };

  ushort8 g1[2][2], g2[2][2], g3[2][2], g4[2][2];  // [slot][chunk]
  ushort8 bv[2];                                   // [chunk]
  auto issueA = [&](int ktg2, auto slotc, bool doParams) {
    constexpr int slot = decltype(slotc)::value;
    if (doParams) {
      int kk = ktg2 >> 2;
      params(kk);
      loadom(kk < 8 ? kk + 1 : 8);
    }
    wbuf[slot][0] = cw1; wbuf[slot][1] = cw2; wbuf[slot][2] = cw3; wbuf[slot][3] = cw4;
    int c0 = (ktg2 & 3) * 64 + sc4 * 16;
#pragma unroll
    for (int g = 0; g < 2; ++g) {
      int c = c0 + g * 8;
      g1[slot][g] = *(const ushort8*)(xb + a1 + c);
      g2[slot][g] = *(const ushort8*)(xb + a2 + c);
      g3[slot][g] = *(const ushort8*)(xb + a3 + c);
      g4[slot][g] = *(const ushort8*)(xb + a4 + c);
    }
  };
  auto prefB = [&](int ktg2) {
#pragma unroll
    for (int g = 0; g < 2; ++g)
      bv[g] = *(const ushort8*)(Bg + ktg2 * 64 + g * 8);
  };

  int ktg0 = grp * 18;
  int kk0 = ktg0 >> 2;
  loadom(kk0);
  params(kk0);
  loadom(kk0 < 8 ? kk0 + 1 : 8);
  issueA(ktg0, ic<0>{}, false);
  issueA(ktg0 + 1, ic<1>{}, false);
  prefB(ktg0);

  int mr = lane & 15, q = lane >> 4;

  auto step = [&](int kt, auto slotc) {
    constexpr int slot = decltype(slotc)::value;
    int ktg = ktg0 + kt;
    // blend + perm-pack: gathers were issued at kt-2 -> vmcnt wait ~0
    uint4v rs[2];
#pragma unroll
    for (int g = 0; g < 2; ++g) {
#pragma unroll
      for (int p = 0; p < 4; ++p) {
        float va = wbuf[slot][0] * bf2f(g1[slot][g][2 * p])     + wbuf[slot][1] * bf2f(g2[slot][g][2 * p]) +
                   wbuf[slot][2] * bf2f(g3[slot][g][2 * p])     + wbuf[slot][3] * bf2f(g4[slot][g][2 * p]);
        float vb = wbuf[slot][0] * bf2f(g1[slot][g][2 * p + 1]) + wbuf[slot][1] * bf2f(g2[slot][g][2 * p + 1]) +
                   wbuf[slot][2] * bf2f(g3[slot][g][2 * p + 1]) + wbuf[slot][3] * bf2f(g4[slot][g][2 * p + 1]);
        unsigned ua = __float_as_uint(va) + 0x8000u;
        unsigned ub = __float_as_uint(vb) + 0x8000u;
        rs[g][p] = __builtin_amdgcn_perm(ub, ua, 0x07060302u);
      }
    }
    if (kt + 2 < 18) issueA(ktg + 2, slotc, ((ktg + 2) & 3) == 0);
    LGKM0_BAR();                 // all waves done reading LDS tile kt-1
#pragma unroll
    for (int g = 0; g < 2; ++g) {
      int ch = (sc4 * 2 + g) ^ (srow & 7);
      *(uint4v*)&As[srow * 64 + ch * 8] = rs[g];
      *(ushort8*)&Bs[srow * 64 + ch * 8] = bv[g];
    }
    if (kt + 1 < 18) prefB(ktg + 1);
    LGKM0_BAR();                 // writes visible
#pragma unroll
    for (int kh = 0; kh < 2; ++kh) {
      int coff = ((q + kh * 4) ^ (mr & 7)) * 8;
      bf16x8 af[4], bfv[2];
#pragma unroll
      for (int mt = 0; mt < 4; ++mt)
        af[mt] = *(const bf16x8*)&As[(wm * 64 + mt * 16 + mr) * 64 + coff];
#pragma unroll
      for (int nt = 0; nt < 2; ++nt)
        bfv[nt] = *(const bf16x8*)&Bs[(wn * 32 + nt * 16 + mr) * 64 + coff];
#pragma unroll
      for (int mt = 0; mt < 4; ++mt)
#pragma unroll
        for (int nt = 0; nt < 2; ++nt)
          acc[mt][nt] = __builtin_amdgcn_mfma_f32_16x16x32_bf16(af[mt], bfv[nt], acc[mt][nt], 0, 0, 0);
    }
  };

  for (int kp = 0; kp < 9; ++kp) {
    step(2 * kp, ic<0>{});
    step(2 * kp + 1, ic<1>{});
  }

  // reduce K-partials through LDS
  float* scratch = (float*)&SH[0][0];
  __syncthreads();
  if (grp == 1) {
#pragma unroll
    for (int mt = 0; mt < 4; ++mt)
#pragma unroll
      for (int nt = 0; nt < 2; ++nt) {
        int pl = wm * 64 + mt * 16 + q * 4;
        int ol = wn * 32 + nt * 16 + mr;
#pragma unroll
        for (int rg = 0; rg < 4; ++rg)
          scratch[(pl + rg) * 128 + ol] = acc[mt][nt][rg];
      }
  }
  __syncthreads();
  if (grp == 0) {
#pragma unroll
    for (int mt = 0; mt < 4; ++mt)
#pragma unroll
      for (int nt = 0; nt < 2; ++nt) {
        int pl = wm * 64 + mt * 16 + q * 4;
        int ol = wn * 32 + nt * 16 + mr;
        f32x4 v = acc[mt][nt];
#pragma unroll
        for (int rg = 0; rg < 4; ++rg) v[rg] += scratch[(pl + rg) * 128 + ol];
        int p = r0 + pl;
        int o = o0 + ol;
        int nn = p >> 12, pyx = p & 4095;
        *(f32x4*)(out + ((size_t)(nn * 256 + o) << 12) + pyx) = v;
      }
  }
}

extern "C" void kernel_launch(void* const* d_in, const int* in_sizes, int n_in,
                              void* d_out, int out_size, void* d_ws, size_t ws_size,
                              hipStream_t stream) {
  const float* x     = (const float*)d_in[0];
  const float* w_off = (const float*)d_in[1];
  const float* b_off = (const float*)d_in[2];
  const float* dcn_w = (const float*)d_in[3];
  float* out = (float*)d_out;
  char* ws = (char*)d_ws;
  unsigned short* xbf   = (unsigned short*)(ws + XBF_OFF);
  unsigned short* wrep  = (unsigned short*)(ws + WREP_OFF);
  unsigned short* wmain = (unsigned short*)(ws + WMAIN_OFF);
  float*          om    = (float*)(ws + OM_OFF);

  k_pre<<<2048 + 288, 256, 0, stream>>>(x, w_off, dcn_w, xbf, wrep, wmain);
  k_offconv<<<256, 1024, 0, stream>>>(xbf, wrep, b_off, om);
  k_gemm_fused<<<dim3(128, 2), 1024, 0, stream>>>(xbf, om, wmain, out);
}

// Round 9
// 131.549 us; speedup vs baseline: 5.5090x; 2.6024x over previous
//
#include <hip/hip_runtime.h>
#include <type_traits>

// DCNv2 forward, MI355X (gfx950).
//  k_pre:        x NCHW f32 -> xbf NHWC bf16 + coalesced weight repack.
//  k_offconv:    implicit-im2col MFMA GEMM -> om[r][32] f32 (bias+sigmoid).
//  k_gemm_fused: deformable-im2col fused GEMM. 1024 thr = 16 waves in a 4x4
//                wave grid (32x32 wave tile), NO K-split: each thread samples
//                8 channels -> depth-2 gather state fits the 128-reg/thread cap
//                (R8 lesson: 1024-thr blocks cap at 128 VGPR+AGPR; 16-ch
//                sampling + split acc = 180 regs = 1.2 GB scratch spill).
//                Triple-buffered LDS tiles, ONE lgkm-only barrier per kstep,
//                blend(k) consumes gathers issued at k-2 (~2 iters of cover).
//                slot/buf indices are integral_constants (6-step unroll).

typedef __bf16 bf16x8 __attribute__((ext_vector_type(8)));
typedef float  f32x4  __attribute__((ext_vector_type(4)));
typedef unsigned short ushort8 __attribute__((ext_vector_type(8)));
typedef unsigned int   uint4v  __attribute__((ext_vector_type(4)));

#define XBF_OFF   0u            // 4*4096*256*2  = 8,388,608
#define WREP_OFF  8388608u      // 32*2304*2     =   147,456
#define WMAIN_OFF 8536064u      // 256*2304*2    = 1,179,648
#define OM_OFF    9715712u      // 16384*32*4    = 2,097,152

// wait lgkmcnt(0) only (vmcnt=no wait), then barrier.
#define LGKM0_BAR() do { __builtin_amdgcn_s_waitcnt(0xC07F); __builtin_amdgcn_s_barrier(); } while (0)

template <int N> using ic = std::integral_constant<int, N>;

__device__ __forceinline__ unsigned short f2bf(float f) {
  unsigned int u = __float_as_uint(f);
  u += 0x7fffu + ((u >> 16) & 1u);
  return (unsigned short)(u >> 16);
}
__device__ __forceinline__ float bf2f(unsigned short h) {
  return __uint_as_float(((unsigned int)h) << 16);
}

// ---------------- merged transpose + coalesced repack ----------------
__global__ __launch_bounds__(256) void k_pre(const float* __restrict__ x,
                                             const float* __restrict__ w_off,
                                             const float* __restrict__ dcn_w,
                                             unsigned short* __restrict__ xbf,
                                             unsigned short* __restrict__ wrep,
                                             unsigned short* __restrict__ wmain) {
  __shared__ float tile[32][65];
  __shared__ unsigned short lsh[2304];
  int b = blockIdx.x;
  int t = threadIdx.x;
  if (b < 2048) {               // transpose role
    int n  = b >> 9;
    int cb = (b >> 6) & 7;
    int xb = b & 63;
    int xx  = t & 63;
    int cc0 = t >> 6;
#pragma unroll
    for (int j = 0; j < 8; ++j) {
      int cc = cc0 + j * 4;
      tile[cc][xx] = x[((size_t)(n * 256 + cb * 32 + cc) << 12) + xb * 64 + xx];
    }
    __syncthreads();
    int ccw = t & 31;
    int xw0 = t >> 5;
#pragma unroll
    for (int j = 0; j < 8; ++j) {
      int xw = xw0 + j * 8;
      xbf[((size_t)((n << 12) + xb * 64 + xw)) * 256 + cb * 32 + ccw] = f2bf(tile[ccw][xw]);
    }
  } else {                      // repack role: one block per output channel
    int ocb = b - 2048;
    const float* src;
    unsigned short* dst;
    int oc;
    if (ocb < 32) { oc = ocb; src = w_off; dst = wrep; }
    else          { oc = ocb - 32; src = dcn_w; dst = wmain; }
    if (ocb < 32 && oc >= 27) {
#pragma unroll
      for (int j = 0; j < 9; ++j) dst[oc * 2304 + j * 256 + t] = 0;
      return;
    }
    const float* base = src + (size_t)oc * 2304;
#pragma unroll
    for (int j = 0; j < 9; ++j) lsh[j * 256 + t] = f2bf(base[t * 9 + j]);
    __syncthreads();
#pragma unroll
    for (int j = 0; j < 9; ++j) dst[oc * 2304 + j * 256 + t] = lsh[j * 256 + t];
  }
}

// ---------------- offset-field conv: K-split-4, BK=64, depth-2 prefetch ------
__global__ __launch_bounds__(1024) void k_offconv(const unsigned short* __restrict__ xbf,
                                                  const unsigned short* __restrict__ wrep,
                                                  const float* __restrict__ bias,
                                                  float* __restrict__ om) {
  __shared__ __align__(16) unsigned short SHa[4][64 * 64];
  __shared__ __align__(16) unsigned short SHb[4][32 * 64];
  int t = threadIdx.x;
  int wave = t >> 6, lane = t & 63;
  int grp = wave >> 2, wv = wave & 3;
  int tg = t & 255;
  int bm = ((blockIdx.x & 7) << 5) + (blockIdx.x >> 3);   // XCD swizzle
  int n = bm >> 6, oy = bm & 63;

  unsigned short* As = SHa[grp];
  unsigned short* Bs = SHb[grp];

  int arow = tg >> 2, acc4 = tg & 3;
  int brow = tg >> 3, bch = tg & 7;

  f32x4 acc0 = {0.f, 0.f, 0.f, 0.f};
  f32x4 acc1 = {0.f, 0.f, 0.f, 0.f};

  ushort8 av[2][2]; ushort8 bv[2];
  auto prefetch = [&](int ktg, auto slotc) {
    constexpr int slot = decltype(slotc)::value;
    int kk = ktg >> 2;
    int c0 = (ktg & 3) * 64;
    int dy = kk / 3 - 1, dx = kk % 3 - 1;
    int yy = oy + dy, xxg = arow + dx;
    bool ok = ((unsigned)yy < 64u) && ((unsigned)xxg < 64u);
    const unsigned short* p = xbf + (size_t)(((n * 64 + yy) * 64 + xxg) * 256 + c0 + acc4 * 16);
#pragma unroll
    for (int g = 0; g < 2; ++g)
      av[slot][g] = ok ? *(const ushort8*)(p + g * 8) : (ushort8){0,0,0,0,0,0,0,0};
    bv[slot] = *(const ushort8*)(wrep + (size_t)brow * 2304 + ktg * 64 + bch * 8);
  };

  int k0 = grp * 9;
  prefetch(k0, ic<0>{});
  prefetch(k0 + 1, ic<1>{});
  int mr = lane & 15, q = lane >> 4;

  auto step = [&](int kt, auto slotc) {
    constexpr int slot = decltype(slotc)::value;
    LGKM0_BAR();
#pragma unroll
    for (int g = 0; g < 2; ++g) {
      int ch = (acc4 * 2 + g) ^ (arow & 7);
      *(ushort8*)&As[arow * 64 + ch * 8] = av[slot][g];
    }
    { int ch = bch ^ (brow & 7);
      *(ushort8*)&Bs[brow * 64 + ch * 8] = bv[slot]; }
    if (kt + 2 < 9) prefetch(k0 + kt + 2, slotc);
    LGKM0_BAR();
#pragma unroll
    for (int kh = 0; kh < 2; ++kh) {
      int coff = ((q + kh * 4) ^ (mr & 7)) * 8;
      bf16x8 a  = *(const bf16x8*)&As[(wv * 16 + mr) * 64 + coff];
      bf16x8 b0 = *(const bf16x8*)&Bs[mr * 64 + coff];
      bf16x8 b1 = *(const bf16x8*)&Bs[(16 + mr) * 64 + coff];
      acc0 = __builtin_amdgcn_mfma_f32_16x16x32_bf16(a, b0, acc0, 0, 0, 0);
      acc1 = __builtin_amdgcn_mfma_f32_16x16x32_bf16(a, b1, acc1, 0, 0, 0);
    }
  };
  for (int kp = 0; kp < 4; ++kp) {
    step(2 * kp, ic<0>{});
    step(2 * kp + 1, ic<1>{});
  }
  step(8, ic<0>{});

  float* scratch = (float*)&SHa[0][0];
  __syncthreads();
  if (grp > 0) {
#pragma unroll
    for (int nt = 0; nt < 2; ++nt) {
      f32x4 a = nt ? acc1 : acc0;
#pragma unroll
      for (int rg = 0; rg < 4; ++rg)
        scratch[(grp - 1) * 2048 + (wv * 16 + q * 4 + rg) * 32 + nt * 16 + mr] = a[rg];
    }
  }
  __syncthreads();
  if (grp == 0) {
    int r0 = bm * 64;
#pragma unroll
    for (int nt = 0; nt < 2; ++nt) {
      f32x4 a = nt ? acc1 : acc0;
      int oc = nt * 16 + mr;
      float bvl = (oc < 27) ? bias[oc] : 0.f;
#pragma unroll
      for (int rg = 0; rg < 4; ++rg) {
        int pl = wv * 16 + q * 4 + rg;
        float v = a[rg] + bvl + scratch[pl * 32 + oc] +
                  scratch[2048 + pl * 32 + oc] + scratch[4096 + pl * 32 + oc];
        if (oc >= 18 && oc < 27) v = 1.f / (1.f + __expf(-v));
        om[(r0 + pl) * 32 + oc] = v;
      }
    }
  }
}

// ---------------- fused deformable-im2col GEMM v3 ----------------------------
// 1024 thr, 4x4 wave grid, 8 ch/thread sampling, triple-buffered LDS,
// 1 lgkm barrier per kstep, depth-2 register prefetch for A-gathers and B.
__global__ __launch_bounds__(1024) void k_gemm_fused(const unsigned short* __restrict__ xbf,
                                                     const float* __restrict__ om,
                                                     const unsigned short* __restrict__ wB,
                                                     float* __restrict__ out) {
  __shared__ __align__(16) unsigned short Ab[3][128 * 64];  // 48 KB
  __shared__ __align__(16) unsigned short Bb[3][128 * 64];  // 48 KB
  int t = threadIdx.x;
  int wave = t >> 6, lane = t & 63;
  int wm = wave & 3, wn = wave >> 2;
  int bmx = ((blockIdx.x & 7) << 4) + (blockIdx.x >> 3);    // XCD swizzle
  int r0 = bmx * 128, o0 = blockIdx.y * 128;

  int srow = t >> 3;            // 0..127
  int sch  = (t & 7) * 8;       // channel / k chunk offset
  int r = r0 + srow;
  int n = r >> 12, yx = r & 4095, oy = yx >> 6, ox = yx & 63;
  const unsigned short* xb = xbf + (size_t)n * (4096 * 256);
  const float* omr = om + (size_t)r * 32;
  const unsigned short* Bg = wB + (size_t)(o0 + srow) * 2304 + sch;
  int wch = ((t & 7) ^ (srow & 7)) * 8;   // swizzled write offset

  f32x4 acc[2][2];
#pragma unroll
  for (int mt = 0; mt < 2; ++mt)
#pragma unroll
    for (int nt = 0; nt < 2; ++nt) acc[mt][nt] = (f32x4){0.f, 0.f, 0.f, 0.f};

  float pv_y, pv_x, pv_m;
  float cw1, cw2, cw3, cw4;
  int a1, a2, a3, a4;
  float wbuf[2][4];

  auto loadom = [&](int kk) {
    pv_y = omr[2 * kk]; pv_x = omr[2 * kk + 1]; pv_m = omr[18 + kk];
  };
  auto params = [&](int kk) {        // consumes pv_* (already resident)
    float py = (float)(oy + kk / 3) + pv_y;
    float px = (float)(ox + kk % 3) + pv_x;
    float m = pv_m;
    py = fminf(fmaxf(py, 0.f), 65.f);
    px = fminf(fmaxf(px, 0.f), 65.f);
    float fy = floorf(py), fx = floorf(px);
    float ly = py - fy, lx = px - fx;
    float hy = 1.f - ly, hx = 1.f - lx;
    int iy = (int)fy, ix = (int)fx;
    bool yv0 = (iy >= 1) && (iy <= 64);
    bool yv1 = (iy <= 63);
    bool xv0 = (ix >= 1) && (ix <= 64);
    bool xv1 = (ix <= 63);
    int y0 = min(max(iy - 1, 0), 63);
    int y1 = min(iy, 63);
    int x0 = min(max(ix - 1, 0), 63);
    int x1 = min(ix, 63);
    cw1 = (yv0 && xv0) ? hy * hx * m : 0.f;
    cw2 = (yv0 && xv1) ? hy * lx * m : 0.f;
    cw3 = (yv1 && xv0) ? ly * hx * m : 0.f;
    cw4 = (yv1 && xv1) ? ly * lx * m : 0.f;
    a1 = ((y0 << 6) + x0) * 256;
    a2 = ((y0 << 6) + x1) * 256;
    a3 = ((y1 << 6) + x0) * 256;
    a4 = ((y1 << 6) + x1) * 256;
  };

  ushort8 g1[2], g2[2], g3[2], g4[2], bv[2];
  auto issueA = [&](int ktg, auto slotc) {
    constexpr int slot = decltype(slotc)::value;
    wbuf[slot][0] = cw1; wbuf[slot][1] = cw2; wbuf[slot][2] = cw3; wbuf[slot][3] = cw4;
    int c = (ktg & 3) * 64 + sch;
    g1[slot] = *(const ushort8*)(xb + a1 + c);
    g2[slot] = *(const ushort8*)(xb + a2 + c);
    g3[slot] = *(const ushort8*)(xb + a3 + c);
    g4[slot] = *(const ushort8*)(xb + a4 + c);
  };
  auto issueB = [&](int ktg, auto slotc) {
    constexpr int slot = decltype(slotc)::value;
    bv[slot] = *(const ushort8*)(Bg + ktg * 64);
  };

  loadom(0);
  params(0);
  loadom(1);
  issueA(0, ic<0>{}); issueB(0, ic<0>{});
  issueA(1, ic<1>{}); issueB(1, ic<1>{});

  int mr = lane & 15, q = lane >> 4;

  auto step = [&](int k, auto slotc, auto bufc) {
    constexpr int slot = decltype(slotc)::value;
    constexpr int buf  = decltype(bufc)::value;
    // W(k): blend + perm-pack (vmcnt waits gathers issued at k-2)
    uint4v rs;
#pragma unroll
    for (int p = 0; p < 4; ++p) {
      float va = wbuf[slot][0] * bf2f(g1[slot][2 * p])     + wbuf[slot][1] * bf2f(g2[slot][2 * p]) +
                 wbuf[slot][2] * bf2f(g3[slot][2 * p])     + wbuf[slot][3] * bf2f(g4[slot][2 * p]);
      float vb = wbuf[slot][0] * bf2f(g1[slot][2 * p + 1]) + wbuf[slot][1] * bf2f(g2[slot][2 * p + 1]) +
                 wbuf[slot][2] * bf2f(g3[slot][2 * p + 1]) + wbuf[slot][3] * bf2f(g4[slot][2 * p + 1]);
      unsigned ua = __float_as_uint(va) + 0x8000u;
      unsigned ub = __float_as_uint(vb) + 0x8000u;
      rs[p] = __builtin_amdgcn_perm(ub, ua, 0x07060302u);
    }
    // S(k): store A + B into buf (safe: last reader M(k-3) drained 2 bars ago)
    *(uint4v*)&Ab[buf][srow * 64 + wch] = rs;
    *(ushort8*)&Bb[buf][srow * 64 + wch] = bv[slot];
    // issue k+2 (reuses slot, now free)
    if (k + 2 < 36) {
      if (((k + 2) & 3) == 0) {
        int kk = (k + 2) >> 2;
        params(kk);
        loadom(kk < 8 ? kk + 1 : 8);
      }
      issueA(k + 2, slotc);
      issueB(k + 2, slotc);
    }
    LGKM0_BAR();                 // S(k) visible to all; gathers stay in flight
    // M(k)
#pragma unroll
    for (int kh = 0; kh < 2; ++kh) {
      int coff = ((q + kh * 4) ^ (mr & 7)) * 8;
      bf16x8 af[2], bfv[2];
#pragma unroll
      for (int mt = 0; mt < 2; ++mt)
        af[mt] = *(const bf16x8*)&Ab[buf][(wm * 32 + mt * 16 + mr) * 64 + coff];
#pragma unroll
      for (int nt = 0; nt < 2; ++nt)
        bfv[nt] = *(const bf16x8*)&Bb[buf][(wn * 32 + nt * 16 + mr) * 64 + coff];
#pragma unroll
      for (int mt = 0; mt < 2; ++mt)
#pragma unroll
        for (int nt = 0; nt < 2; ++nt)
          acc[mt][nt] = __builtin_amdgcn_mfma_f32_16x16x32_bf16(af[mt], bfv[nt], acc[mt][nt], 0, 0, 0);
    }
  };

  for (int kp = 0; kp < 6; ++kp) {
    int k = kp * 6;
    step(k + 0, ic<0>{}, ic<0>{});
    step(k + 1, ic<1>{}, ic<1>{});
    step(k + 2, ic<0>{}, ic<2>{});
    step(k + 3, ic<1>{}, ic<0>{});
    step(k + 4, ic<0>{}, ic<1>{});
    step(k + 5, ic<1>{}, ic<2>{});
  }

  // epilogue: direct stores (no K-split reduction needed)
#pragma unroll
  for (int mt = 0; mt < 2; ++mt)
#pragma unroll
    for (int nt = 0; nt < 2; ++nt) {
      int p = r0 + wm * 32 + mt * 16 + q * 4;
      int o = o0 + wn * 32 + nt * 16 + mr;
      int nn = p >> 12, pyx = p & 4095;
      *(f32x4*)(out + ((size_t)(nn * 256 + o) << 12) + pyx) = acc[mt][nt];
    }
}

extern "C" void kernel_launch(void* const* d_in, const int* in_sizes, int n_in,
                              void* d_out, int out_size, void* d_ws, size_t ws_size,
                              hipStream_t stream) {
  const float* x     = (const float*)d_in[0];
  const float* w_off = (const float*)d_in[1];
  const float* b_off = (const float*)d_in[2];
  const float* dcn_w = (const float*)d_in[3];
  float* out = (float*)d_out;
  char* ws = (char*)d_ws;
  unsigned short* xbf   = (unsigned short*)(ws + XBF_OFF);
  unsigned short* wrep  = (unsigned short*)(ws + WREP_OFF);
  unsigned short* wmain = (unsigned short*)(ws + WMAIN_OFF);
  float*          om    = (float*)(ws + OM_OFF);

  k_pre<<<2048 + 288, 256, 0, stream>>>(x, w_off, dcn_w, xbf, wrep, wmain);
  k_offconv<<<256, 1024, 0, stream>>>(xbf, wrep, b_off, om);
  k_gemm_fused<<<dim3(128, 2), 1024, 0, stream>>>(xbf, om, wmain, out);
}